// Round 2
// baseline (123.514 us; speedup 1.0000x reference)
//
#include <hip/hip_runtime.h>

#define LOG2E 1.44269504088896340736f

// ---------------- workspace layout (float offsets) ----------------
static constexpr size_t Q_OFF    = 0;          // [128][1024] Q / sqrt(D)
static constexpr size_t K_OFF    = 131072;     // [128][1024]
static constexpr size_t VT_OFF   = 262144;     // [1024][128]  V transposed
static constexpr size_t PN_OFF   = 393216;     // [128][1024]  p + bp1
static constexpr size_t PM_OFF   = 524288;     // [128][1024]  p
static constexpr size_t AO_OFF   = 655360;     // [128][1024]  attention out
static constexpr size_t PACC_OFF = 786432;     // [8][128][1024] partial PV
static constexpr size_t PMAX_OFF = 1835008;    // [8][4][1024]
static constexpr size_t PSUM_OFF = 1867776;    // [8][4][1024]
// total = 1,900,544 floats = 7.25 MB

__device__ __forceinline__ float fast_gelu(float x){
    // 0.5*x*(1+tanh(0.79788456*(x+0.044715 x^3))) == x*u/(u+1),
    // u = exp2(2.3022082*(x + 0.044715 x^3))
    float t = x * fmaf(x*x, 0.044715f, 1.0f);
    float a = t * 2.3022082f;
    a = fminf(fmaxf(a, -60.0f), 60.0f);          // overflow-safe
    float u = __builtin_amdgcn_exp2f(a);
    return x * u * __builtin_amdgcn_rcpf(u + 1.0f);
}

__device__ __forceinline__ float wave_max64(float v){
    #pragma unroll
    for (int m = 32; m >= 1; m >>= 1) v = fmaxf(v, __shfl_xor(v, m, 64));
    return v;
}
__device__ __forceinline__ float wave_sum64(float v){
    #pragma unroll
    for (int m = 32; m >= 1; m >>= 1) v += __shfl_xor(v, m, 64);
    return v;
}

// ---------------- kernel 1: projections ----------------
// grid (64, 4): x = n-tile of 16, y = mat (0=Q,1=K,2=V,3=pos-proj)
__global__ __launch_bounds__(256) void k_prep(
    const float* __restrict__ x, const float* __restrict__ xyz,
    const float* __restrict__ Wq, const float* __restrict__ Wk,
    const float* __restrict__ Wv, const float* __restrict__ Wp1,
    const float* __restrict__ bp1, float* __restrict__ ws)
{
    const int t   = threadIdx.x;
    const int mat = blockIdx.y;
    const int n0  = blockIdx.x * 16;

    if (mat == 3){   // p[c,n] = Wp1[c]·xyz[n]
        const int c = t & 127, ng = t >> 7;
        const float w0 = Wp1[c*3+0], w1 = Wp1[c*3+1], w2 = Wp1[c*3+2];
        const float b  = bp1[c];
        #pragma unroll
        for (int i = 0; i < 8; i++){
            const int n = n0 + ng*8 + i;
            float p = w0*xyz[n*3+0] + w1*xyz[n*3+1] + w2*xyz[n*3+2];
            ws[PM_OFF + (size_t)c*1024 + n] = p;
            ws[PN_OFF + (size_t)c*1024 + n] = p + b;
        }
        return;
    }

    __shared__ float wlds[128*129];   // [c][k] pitch 129 -> conflict-free
    __shared__ float xlds[128*16];    // [k][n16]
    const float* W = (mat == 0) ? Wq : (mat == 1 ? Wk : Wv);
    for (int i = t; i < 16384; i += 256)
        wlds[(i>>7)*129 + (i&127)] = W[i];
    for (int i = t; i < 2048; i += 256)
        xlds[i] = x[(size_t)(i>>4)*1024 + n0 + (i&15)];
    __syncthreads();

    const int c = t & 127, ng = t >> 7;
    float acc[8] = {0,0,0,0,0,0,0,0};
    #pragma unroll 4
    for (int k = 0; k < 128; k++){
        const float wv = wlds[c*129 + k];
        const float4 a0 = *(const float4*)&xlds[k*16 + ng*8];
        const float4 a1 = *(const float4*)&xlds[k*16 + ng*8 + 4];
        acc[0] = fmaf(wv, a0.x, acc[0]);
        acc[1] = fmaf(wv, a0.y, acc[1]);
        acc[2] = fmaf(wv, a0.z, acc[2]);
        acc[3] = fmaf(wv, a0.w, acc[3]);
        acc[4] = fmaf(wv, a1.x, acc[4]);
        acc[5] = fmaf(wv, a1.y, acc[5]);
        acc[6] = fmaf(wv, a1.z, acc[6]);
        acc[7] = fmaf(wv, a1.w, acc[7]);
    }

    if (mat == 0){
        #pragma unroll
        for (int i = 0; i < 8; i++) acc[i] *= 0.17677669529663689f; // 1/sqrt(32)
        float4* dst = (float4*)&ws[Q_OFF + (size_t)c*1024 + n0 + ng*8];
        dst[0] = make_float4(acc[0],acc[1],acc[2],acc[3]);
        dst[1] = make_float4(acc[4],acc[5],acc[6],acc[7]);
    } else if (mat == 1){
        float4* dst = (float4*)&ws[K_OFF + (size_t)c*1024 + n0 + ng*8];
        dst[0] = make_float4(acc[0],acc[1],acc[2],acc[3]);
        dst[1] = make_float4(acc[4],acc[5],acc[6],acc[7]);
    } else {
        #pragma unroll
        for (int i = 0; i < 8; i++){
            const int n = n0 + ng*8 + i;
            ws[VT_OFF + (size_t)n*128 + c] = acc[i];   // V transposed
        }
    }
}

// ---------------- kernel 2: fused scores + chunk softmax + partial PV ----
// grid (64, 8): x = n-tile of 16, y = m-chunk of 128. block 256 (4 waves).
__global__ __launch_bounds__(256) void k_attn(
    const float* __restrict__ Wp2, const float* __restrict__ bp2,
    float* __restrict__ ws)
{
    __shared__ float slds[4*16*128];  // [h][n16][m128] scores -> exp
    __shared__ float wbar[128*4];     // [c][h]
    __shared__ float bbar[4];

    const int t  = threadIdx.x;
    const int bx = blockIdx.x;     // n-tile
    const int by = blockIdx.y;     // m-chunk

    if (t < 128){
        #pragma unroll
        for (int h = 0; h < 4; h++){
            float s = 0.f;
            #pragma unroll 8
            for (int d = 0; d < 32; d++) s += Wp2[(size_t)(h*32+d)*128 + t];
            wbar[t*4 + h] = s * 0.03125f;
        }
    } else if (t < 132){
        const int h = t - 128;
        float s = 0.f;
        for (int d = 0; d < 32; d++) s += bp2[h*32 + d];
        bbar[h] = s * 0.03125f;
    }
    __syncthreads();

    const int lane = t & 63, w = t >> 6;
    const int nbase = bx*16 + w*4;
    const int m0 = by*128 + lane;
    const int m1 = m0 + 64;
    const float* Qp = ws + Q_OFF;
    const float* Kp = ws + K_OFF;
    const float* PN = ws + PN_OFF;
    const float* PM = ws + PM_OFF;

    float acc[4][2][4];
    #pragma unroll
    for (int i = 0; i < 4; i++)
        #pragma unroll
        for (int j = 0; j < 2; j++)
            #pragma unroll
            for (int h = 0; h < 4; h++) acc[i][j][h] = 0.f;

    // c-loop split per head so the QK accumulator index is compile-time
    #pragma unroll
    for (int h = 0; h < 4; h++){
        #pragma unroll 1
        for (int cc = 0; cc < 32; cc++){
            const int c = h*32 + cc;
            const size_t row = (size_t)c*1024;
            const float k0  = Kp[row + m0];
            const float k1  = Kp[row + m1];
            const float pm0 = PM[row + m0];
            const float pm1 = PM[row + m1];
            const float4 q4  = *(const float4*)(Qp + row + nbase);
            const float4 pn4 = *(const float4*)(PN + row + nbase);
            const float4 wb  = *(const float4*)(wbar + c*4);
            const float qs[4] = {q4.x, q4.y, q4.z, q4.w};
            const float ps[4] = {pn4.x, pn4.y, pn4.z, pn4.w};
            #pragma unroll
            for (int i = 0; i < 4; i++){
                const float g0 = fast_gelu(ps[i] - pm0);
                const float g1 = fast_gelu(ps[i] - pm1);
                acc[i][0][0] = fmaf(wb.x, g0, acc[i][0][0]);
                acc[i][0][1] = fmaf(wb.y, g0, acc[i][0][1]);
                acc[i][0][2] = fmaf(wb.z, g0, acc[i][0][2]);
                acc[i][0][3] = fmaf(wb.w, g0, acc[i][0][3]);
                acc[i][1][0] = fmaf(wb.x, g1, acc[i][1][0]);
                acc[i][1][1] = fmaf(wb.y, g1, acc[i][1][1]);
                acc[i][1][2] = fmaf(wb.z, g1, acc[i][1][2]);
                acc[i][1][3] = fmaf(wb.w, g1, acc[i][1][3]);
                acc[i][0][h] = fmaf(qs[i], k0, acc[i][0][h]);
                acc[i][1][h] = fmaf(qs[i], k1, acc[i][1][h]);
            }
        }
    }

    // scores -> LDS
    #pragma unroll
    for (int i = 0; i < 4; i++)
        #pragma unroll
        for (int h = 0; h < 4; h++){
            const int r = h*16 + w*4 + i;
            slds[r*128 + lane]      = acc[i][0][h] + bbar[h];
            slds[r*128 + 64 + lane] = acc[i][1][h] + bbar[h];
        }
    __syncthreads();

    // per-chunk softmax partials; wave w owns rows [w*16, w*16+16)
    for (int r = w*16; r < w*16 + 16; r++){
        const float v0 = slds[r*128 + lane];
        const float v1 = slds[r*128 + 64 + lane];
        const float mx = wave_max64(fmaxf(v0, v1));
        const float e0 = __builtin_amdgcn_exp2f((v0 - mx)*LOG2E);
        const float e1 = __builtin_amdgcn_exp2f((v1 - mx)*LOG2E);
        slds[r*128 + lane]      = e0;
        slds[r*128 + 64 + lane] = e1;
        const float sm = wave_sum64(e0 + e1);
        if (lane == 0){
            const int h = r >> 4, i = r & 15;
            ws[PMAX_OFF + (size_t)(by*4 + h)*1024 + bx*16 + i] = mx;
            ws[PSUM_OFF + (size_t)(by*4 + h)*1024 + bx*16 + i] = sm;
        }
    }
    __syncthreads();

    // partial PV: pacc[c][n] = sum_m e[h(c)][n][m] * V[c][m]
    const int c = t & 127, ng = t >> 7;
    const int h = c >> 5;
    const float* Vt = ws + VT_OFF + (size_t)by*128*128;
    float pv[8] = {0,0,0,0,0,0,0,0};
    #pragma unroll 1
    for (int m = 0; m < 128; m += 4){
        const float v0 = Vt[(size_t)(m+0)*128 + c];
        const float v1 = Vt[(size_t)(m+1)*128 + c];
        const float v2 = Vt[(size_t)(m+2)*128 + c];
        const float v3 = Vt[(size_t)(m+3)*128 + c];
        #pragma unroll
        for (int i = 0; i < 8; i++){
            const float4 e4 = *(const float4*)&slds[(h*16 + ng*8 + i)*128 + m];
            pv[i] = fmaf(e4.x, v0, pv[i]);
            pv[i] = fmaf(e4.y, v1, pv[i]);
            pv[i] = fmaf(e4.z, v2, pv[i]);
            pv[i] = fmaf(e4.w, v3, pv[i]);
        }
    }
    float4* dst = (float4*)&ws[PACC_OFF + (size_t)(by*128 + c)*1024 + bx*16 + ng*8];
    dst[0] = make_float4(pv[0],pv[1],pv[2],pv[3]);
    dst[1] = make_float4(pv[4],pv[5],pv[6],pv[7]);
}

// ---------------- kernel 3: combine chunk partials ----------------
__global__ __launch_bounds__(256) void k_combine(float* __restrict__ ws)
{
    const int idx = blockIdx.x*256 + threadIdx.x;   // 0..131071
    const int c = idx >> 10, n = idx & 1023;
    const int h = c >> 5;
    float pmx[8];
    float mx = -3.4e38f;
    #pragma unroll
    for (int k = 0; k < 8; k++){
        pmx[k] = ws[PMAX_OFF + (size_t)(k*4 + h)*1024 + n];
        mx = fmaxf(mx, pmx[k]);
    }
    float num = 0.f, den = 0.f;
    #pragma unroll
    for (int k = 0; k < 8; k++){
        const float lam = __builtin_amdgcn_exp2f((pmx[k] - mx)*LOG2E);
        den = fmaf(lam, ws[PSUM_OFF + (size_t)(k*4 + h)*1024 + n], den);
        num = fmaf(lam, ws[PACC_OFF + (size_t)(k*128 + c)*1024 + n], num);
    }
    ws[AO_OFF + idx] = num * __builtin_amdgcn_rcpf(den);
}

// ---------------- kernel 4: Wo matmul + bias + residual + LayerNorm ------
// grid (64): n-tile of 16. block 256.
__global__ __launch_bounds__(256) void k_final(
    const float* __restrict__ Wo, const float* __restrict__ bo,
    const float* __restrict__ x, const float* __restrict__ gamma,
    const float* __restrict__ beta, const float* __restrict__ ws,
    float* __restrict__ out)
{
    __shared__ float wlds[128*129];
    __shared__ float alds[128*16];
    __shared__ float stats[32];   // mu[16], rstd[16]
    const int t  = threadIdx.x;
    const int n0 = blockIdx.x * 16;

    for (int i = t; i < 16384; i += 256)
        wlds[(i>>7)*129 + (i&127)] = Wo[i];
    const float* AO = ws + AO_OFF;
    for (int i = t; i < 2048; i += 256)
        alds[i] = AO[(size_t)(i>>4)*1024 + n0 + (i&15)];
    __syncthreads();

    const int c = t & 127, ng = t >> 7;
    float acc[8] = {0,0,0,0,0,0,0,0};
    #pragma unroll 4
    for (int k = 0; k < 128; k++){
        const float wv = wlds[c*129 + k];
        const float4 a0 = *(const float4*)&alds[k*16 + ng*8];
        const float4 a1 = *(const float4*)&alds[k*16 + ng*8 + 4];
        acc[0] = fmaf(wv, a0.x, acc[0]);
        acc[1] = fmaf(wv, a0.y, acc[1]);
        acc[2] = fmaf(wv, a0.z, acc[2]);
        acc[3] = fmaf(wv, a0.w, acc[3]);
        acc[4] = fmaf(wv, a1.x, acc[4]);
        acc[5] = fmaf(wv, a1.y, acc[5]);
        acc[6] = fmaf(wv, a1.z, acc[6]);
        acc[7] = fmaf(wv, a1.w, acc[7]);
    }
    const float bov = bo[c];
    #pragma unroll
    for (int i = 0; i < 8; i++)
        acc[i] += bov + x[(size_t)c*1024 + n0 + ng*8 + i];
    __syncthreads();   // done reading alds

    // LN buffer [n16][c128]
    #pragma unroll
    for (int i = 0; i < 8; i++) alds[(ng*8 + i)*128 + c] = acc[i];
    __syncthreads();

    const int w = t >> 6, lane = t & 63;
    for (int r = w*4; r < w*4 + 4; r++){
        const float v0 = alds[r*128 + lane];
        const float v1 = alds[r*128 + 64 + lane];
        const float s = wave_sum64(v0 + v1);
        const float q = wave_sum64(fmaf(v0, v0, v1*v1));
        if (lane == 0){
            const float mu  = s * 0.0078125f;
            const float var = q * 0.0078125f - mu*mu;
            stats[r]      = mu;
            stats[16 + r] = rsqrtf(var + 1e-5f);
        }
    }
    __syncthreads();

    const float g = gamma[c], b = beta[c];
    #pragma unroll
    for (int i = 0; i < 8; i++){
        const int nn = ng*8 + i;
        out[(size_t)c*1024 + n0 + nn] = (acc[i] - stats[nn]) * stats[16 + nn] * g + b;
    }
}

extern "C" void kernel_launch(void* const* d_in, const int* in_sizes, int n_in,
                              void* d_out, int out_size, void* d_ws, size_t ws_size,
                              hipStream_t stream)
{
    const float* x     = (const float*)d_in[0];
    const float* xyz   = (const float*)d_in[1];
    const float* Wq    = (const float*)d_in[2];
    const float* Wk    = (const float*)d_in[3];
    const float* Wv    = (const float*)d_in[4];
    const float* Wp1   = (const float*)d_in[5];
    const float* bp1   = (const float*)d_in[6];
    const float* Wp2   = (const float*)d_in[7];
    const float* bp2   = (const float*)d_in[8];
    const float* Wo    = (const float*)d_in[9];
    const float* bo    = (const float*)d_in[10];
    const float* gamma = (const float*)d_in[11];
    const float* beta  = (const float*)d_in[12];
    float* ws  = (float*)d_ws;
    float* out = (float*)d_out;

    hipLaunchKernelGGL(k_prep,    dim3(64, 4), dim3(256), 0, stream,
                       x, xyz, Wq, Wk, Wv, Wp1, bp1, ws);
    hipLaunchKernelGGL(k_attn,    dim3(64, 8), dim3(256), 0, stream,
                       Wp2, bp2, ws);
    hipLaunchKernelGGL(k_combine, dim3(512),   dim3(256), 0, stream, ws);
    hipLaunchKernelGGL(k_final,   dim3(64),    dim3(256), 0, stream,
                       Wo, bo, x, gamma, beta, ws, out);
}

// Round 3
// 85.483 us; speedup vs baseline: 1.4449x; 1.4449x over previous
//
#include <hip/hip_runtime.h>

#define LOG2E 1.44269504088896340736f
#define C2G   0.39894228040143267794f   // 1/sqrt(2*pi)
#define K2M  -0.79788456080286535588f   // -2*C2G

// ---------------- workspace layout (float offsets) ----------------
static constexpr size_t Q_OFF    = 0;          // [128][1024] Q / sqrt(D)
static constexpr size_t K_OFF    = 131072;     // [128][1024]
static constexpr size_t VT_OFF   = 262144;     // [1024][128]  V transposed
static constexpr size_t PM_OFF   = 393216;     // [128][1024]  p = Wp1·xyz
static constexpr size_t AO_OFF   = 524288;     // [128][1024]  attention out
static constexpr size_t PACC_OFF = 655360;     // [8][128][1024] partial PV
static constexpr size_t PMAX_OFF = 1703936;    // [8][4][1024]
static constexpr size_t PSUM_OFF = 1736704;    // [8][4][1024]
static constexpr size_t WBAR_OFF = 1769472;    // [128][4]  wbar[c][h]
static constexpr size_t ROWT_OFF = 1769984;    // [4][1024]
static constexpr size_t COLT_OFF = 1774080;    // [4][1024]
// total = 1,778,176 floats = 6.78 MB

__device__ __forceinline__ float wave_max64(float v){
    #pragma unroll
    for (int m = 32; m >= 1; m >>= 1) v = fmaxf(v, __shfl_xor(v, m, 64));
    return v;
}
__device__ __forceinline__ float wave_sum64(float v){
    #pragma unroll
    for (int m = 32; m >= 1; m >>= 1) v += __shfl_xor(v, m, 64);
    return v;
}

// ---------------- kernel 1: projections ----------------
// grid (64, 4): x = n-tile of 16, y = mat (0=Q,1=K,2=V,3=pos-proj)
__global__ __launch_bounds__(256) void k_prep(
    const float* __restrict__ x, const float* __restrict__ xyz,
    const float* __restrict__ Wq, const float* __restrict__ Wk,
    const float* __restrict__ Wv, const float* __restrict__ Wp1,
    float* __restrict__ ws)
{
    const int t   = threadIdx.x;
    const int mat = blockIdx.y;
    const int n0  = blockIdx.x * 16;

    if (mat == 3){   // p[c,n] = Wp1[c]·xyz[n]
        const int c = t & 127, ng = t >> 7;
        const float w0 = Wp1[c*3+0], w1 = Wp1[c*3+1], w2 = Wp1[c*3+2];
        #pragma unroll
        for (int i = 0; i < 8; i++){
            const int n = n0 + ng*8 + i;
            float p = w0*xyz[n*3+0] + w1*xyz[n*3+1] + w2*xyz[n*3+2];
            ws[PM_OFF + (size_t)c*1024 + n] = p;
        }
        return;
    }

    __shared__ float wlds[128*129];   // [c][k] pitch 129 -> conflict-free
    __shared__ float xlds[128*16];    // [k][n16]
    const float* W = (mat == 0) ? Wq : (mat == 1 ? Wk : Wv);
    for (int i = t; i < 16384; i += 256)
        wlds[(i>>7)*129 + (i&127)] = W[i];
    for (int i = t; i < 2048; i += 256)
        xlds[i] = x[(size_t)(i>>4)*1024 + n0 + (i&15)];
    __syncthreads();

    const int c = t & 127, ng = t >> 7;
    float acc[8] = {0,0,0,0,0,0,0,0};
    #pragma unroll 4
    for (int k = 0; k < 128; k++){
        const float wv = wlds[c*129 + k];
        const float4 a0 = *(const float4*)&xlds[k*16 + ng*8];
        const float4 a1 = *(const float4*)&xlds[k*16 + ng*8 + 4];
        acc[0] = fmaf(wv, a0.x, acc[0]);
        acc[1] = fmaf(wv, a0.y, acc[1]);
        acc[2] = fmaf(wv, a0.z, acc[2]);
        acc[3] = fmaf(wv, a0.w, acc[3]);
        acc[4] = fmaf(wv, a1.x, acc[4]);
        acc[5] = fmaf(wv, a1.y, acc[5]);
        acc[6] = fmaf(wv, a1.z, acc[6]);
        acc[7] = fmaf(wv, a1.w, acc[7]);
    }

    if (mat == 0){
        #pragma unroll
        for (int i = 0; i < 8; i++) acc[i] *= 0.17677669529663689f; // 1/sqrt(32)
        float4* dst = (float4*)&ws[Q_OFF + (size_t)c*1024 + n0 + ng*8];
        dst[0] = make_float4(acc[0],acc[1],acc[2],acc[3]);
        dst[1] = make_float4(acc[4],acc[5],acc[6],acc[7]);
    } else if (mat == 1){
        float4* dst = (float4*)&ws[K_OFF + (size_t)c*1024 + n0 + ng*8];
        dst[0] = make_float4(acc[0],acc[1],acc[2],acc[3]);
        dst[1] = make_float4(acc[4],acc[5],acc[6],acc[7]);
    } else {
        #pragma unroll
        for (int i = 0; i < 8; i++){
            const int n = n0 + ng*8 + i;
            ws[VT_OFF + (size_t)n*128 + c] = acc[i];   // V transposed
        }
    }
}

// ---------------- kernel 1b: wbar / bbar / ROWT / COLT ----------------
// Quadratic gelu expansion: gelu(pn - pm + b1) ~= 0.5x + C2G x^2 separates:
//   ROWT[h,n] = sum_c w*( (0.5+2*C2G*b1)*p + C2G*p^2 + 0.5*b1 + C2G*b1^2 ) + bbar
//   COLT[h,m] = sum_c w*( -(0.5+2*C2G*b1)*p + C2G*p^2 )
//   cross     = K2M * sum_c w * p_n * p_m   (handled in k_attn)
// grid (64): n-tile of 16.
__global__ __launch_bounds__(256) void k_prep2(
    const float* __restrict__ Wp2, const float* __restrict__ bp2,
    const float* __restrict__ bp1, float* __restrict__ ws)
{
    __shared__ float wb[4][128];
    __shared__ float bb[4];
    __shared__ float pt[128][17];
    const int t  = threadIdx.x;
    const int n0 = blockIdx.x * 16;

    for (int idx = t; idx < 512; idx += 256){
        const int h = idx >> 7, c = idx & 127;
        float s = 0.f;
        #pragma unroll 8
        for (int d = 0; d < 32; d++) s += Wp2[(size_t)(h*32+d)*128 + c];
        wb[h][c] = s * 0.03125f;
    }
    if (t < 4){
        float s = 0.f;
        #pragma unroll 8
        for (int d = 0; d < 32; d++) s += bp2[t*32+d];
        bb[t] = s * 0.03125f;
    }
    for (int i = t; i < 2048; i += 256)
        pt[i>>4][i&15] = ws[PM_OFF + (size_t)(i>>4)*1024 + n0 + (i&15)];
    __syncthreads();

    if (blockIdx.x == 0 && t < 128)
        *(float4*)&ws[WBAR_OFF + t*4] =
            make_float4(wb[0][t], wb[1][t], wb[2][t], wb[3][t]);

    if (t < 64){
        const int h = t >> 4, n = t & 15;
        float ra = 0.f, ca = 0.f;
        for (int c = 0; c < 128; c++){
            const float w  = wb[h][c];
            const float p  = pt[c][n];
            const float b1 = bp1[c];
            const float a  = fmaf(2.f*C2G, b1, 0.5f);
            const float p2 = C2G*p*p;
            ra += w * (a*p + p2 + 0.5f*b1 + C2G*b1*b1);
            ca += w * (p2 - a*p);
        }
        ws[ROWT_OFF + (size_t)h*1024 + n0 + n] = ra + bb[h];
        ws[COLT_OFF + (size_t)h*1024 + n0 + n] = ca;
    }
}

// ---------------- kernel 2: scores + chunk softmax + partial PV ----------
// grid (128, 8): x = n-tile of 8, y = m-chunk of 128. block 256 (4 waves).
// Wave w owns n = bx*8 + w*2 + {0,1}; lane owns m = by*128 + lane + {0,64}.
__global__ __launch_bounds__(256) void k_attn(
    const float* __restrict__ ws_c, float* __restrict__ ws)
{
    __shared__ float slds[32*128];   // [4h*8n][128m] scores -> exp

    const int t    = threadIdx.x;
    const int lane = t & 63, w = t >> 6;
    const int bx   = blockIdx.x, by = blockIdx.y;
    const int nb   = __builtin_amdgcn_readfirstlane(bx*8 + w*2);
    const int m0   = by*128 + lane;
    const int m1   = m0 + 64;

    const float* PM = ws_c + PM_OFF;
    const float* Qp = ws_c + Q_OFF;
    const float* Kp = ws_c + K_OFF;
    const float* WB = ws_c + WBAR_OFF;

    float acc[2][2][4];
    #pragma unroll
    for (int i = 0; i < 2; i++)
        #pragma unroll
        for (int j = 0; j < 2; j++)
            #pragma unroll
            for (int h = 0; h < 4; h++) acc[i][j][h] = 0.f;

    // pos cross term: acc[i][j][h] += wbar[h][c] * (K2M*pm_j) * pn_i
    #pragma unroll 4
    for (int c = 0; c < 128; c++){
        const float  pm0 = PM[(size_t)c*1024 + m0];
        const float  pm1 = PM[(size_t)c*1024 + m1];
        const float2 pn  = *(const float2*)(PM + (size_t)c*1024 + nb); // uniform
        const float4 wb  = *(const float4*)(WB + c*4);                 // uniform
        const float t0 = K2M * pm0;
        const float t1 = K2M * pm1;
        const float u00 = pn.x*t0, u01 = pn.x*t1;
        const float u10 = pn.y*t0, u11 = pn.y*t1;
        acc[0][0][0] = fmaf(wb.x, u00, acc[0][0][0]);
        acc[0][0][1] = fmaf(wb.y, u00, acc[0][0][1]);
        acc[0][0][2] = fmaf(wb.z, u00, acc[0][0][2]);
        acc[0][0][3] = fmaf(wb.w, u00, acc[0][0][3]);
        acc[0][1][0] = fmaf(wb.x, u01, acc[0][1][0]);
        acc[0][1][1] = fmaf(wb.y, u01, acc[0][1][1]);
        acc[0][1][2] = fmaf(wb.z, u01, acc[0][1][2]);
        acc[0][1][3] = fmaf(wb.w, u01, acc[0][1][3]);
        acc[1][0][0] = fmaf(wb.x, u10, acc[1][0][0]);
        acc[1][0][1] = fmaf(wb.y, u10, acc[1][0][1]);
        acc[1][0][2] = fmaf(wb.z, u10, acc[1][0][2]);
        acc[1][0][3] = fmaf(wb.w, u10, acc[1][0][3]);
        acc[1][1][0] = fmaf(wb.x, u11, acc[1][1][0]);
        acc[1][1][1] = fmaf(wb.y, u11, acc[1][1][1]);
        acc[1][1][2] = fmaf(wb.z, u11, acc[1][1][2]);
        acc[1][1][3] = fmaf(wb.w, u11, acc[1][1][3]);
    }

    // QK^T (Q already has 1/sqrt(D))
    #pragma unroll
    for (int h = 0; h < 4; h++){
        #pragma unroll 4
        for (int d = 0; d < 32; d++){
            const size_t r = (size_t)(h*32 + d)*1024;
            const float  k0 = Kp[r + m0];
            const float  k1 = Kp[r + m1];
            const float2 q  = *(const float2*)(Qp + r + nb);   // uniform
            acc[0][0][h] = fmaf(q.x, k0, acc[0][0][h]);
            acc[0][1][h] = fmaf(q.x, k1, acc[0][1][h]);
            acc[1][0][h] = fmaf(q.y, k0, acc[1][0][h]);
            acc[1][1][h] = fmaf(q.y, k1, acc[1][1][h]);
        }
    }

    // affine terms + write scores
    #pragma unroll
    for (int h = 0; h < 4; h++){
        const float rt0 = ws_c[ROWT_OFF + (size_t)h*1024 + nb];
        const float rt1 = ws_c[ROWT_OFF + (size_t)h*1024 + nb + 1];
        const float ct0 = ws_c[COLT_OFF + (size_t)h*1024 + m0];
        const float ct1 = ws_c[COLT_OFF + (size_t)h*1024 + m1];
        slds[(h*8 + w*2 + 0)*128 + lane]      = acc[0][0][h] + rt0 + ct0;
        slds[(h*8 + w*2 + 0)*128 + 64 + lane] = acc[0][1][h] + rt0 + ct1;
        slds[(h*8 + w*2 + 1)*128 + lane]      = acc[1][0][h] + rt1 + ct0;
        slds[(h*8 + w*2 + 1)*128 + 64 + lane] = acc[1][1][h] + rt1 + ct1;
    }
    __syncthreads();

    // per-chunk softmax partials; wave w owns rows [w*8, w*8+8)
    for (int r = w*8; r < w*8 + 8; r++){
        const float v0 = slds[r*128 + lane];
        const float v1 = slds[r*128 + 64 + lane];
        const float mx = wave_max64(fmaxf(v0, v1));
        const float e0 = __builtin_amdgcn_exp2f((v0 - mx)*LOG2E);
        const float e1 = __builtin_amdgcn_exp2f((v1 - mx)*LOG2E);
        slds[r*128 + lane]      = e0;
        slds[r*128 + 64 + lane] = e1;
        const float sm = wave_sum64(e0 + e1);
        if (lane == 0){
            const int h = r >> 3, i = r & 7;
            ws[PMAX_OFF + (size_t)(by*4 + h)*1024 + bx*8 + i] = mx;
            ws[PSUM_OFF + (size_t)(by*4 + h)*1024 + bx*8 + i] = sm;
        }
    }
    __syncthreads();

    // partial PV: pacc[c][n] = sum_m e[h(c)][n][m] * V[c][m]
    const int c = t & 127, ng = t >> 7;
    const int h = c >> 5;
    const float* Vt = ws_c + VT_OFF + (size_t)by*128*128;
    float pv[4] = {0,0,0,0};
    #pragma unroll 1
    for (int m = 0; m < 128; m += 4){
        const float v0 = Vt[(size_t)(m+0)*128 + c];
        const float v1 = Vt[(size_t)(m+1)*128 + c];
        const float v2 = Vt[(size_t)(m+2)*128 + c];
        const float v3 = Vt[(size_t)(m+3)*128 + c];
        #pragma unroll
        for (int i = 0; i < 4; i++){
            const float4 e4 = *(const float4*)&slds[(h*8 + ng*4 + i)*128 + m];
            pv[i] = fmaf(e4.x, v0, pv[i]);
            pv[i] = fmaf(e4.y, v1, pv[i]);
            pv[i] = fmaf(e4.z, v2, pv[i]);
            pv[i] = fmaf(e4.w, v3, pv[i]);
        }
    }
    *(float4*)&ws[PACC_OFF + (size_t)(by*128 + c)*1024 + bx*8 + ng*4] =
        make_float4(pv[0], pv[1], pv[2], pv[3]);
}

// ---------------- kernel 3: combine chunk partials ----------------
__global__ __launch_bounds__(256) void k_combine(float* __restrict__ ws)
{
    const int idx = blockIdx.x*256 + threadIdx.x;   // 0..131071
    const int c = idx >> 10, n = idx & 1023;
    const int h = c >> 5;
    float pmx[8];
    float mx = -3.4e38f;
    #pragma unroll
    for (int k = 0; k < 8; k++){
        pmx[k] = ws[PMAX_OFF + (size_t)(k*4 + h)*1024 + n];
        mx = fmaxf(mx, pmx[k]);
    }
    float num = 0.f, den = 0.f;
    #pragma unroll
    for (int k = 0; k < 8; k++){
        const float lam = __builtin_amdgcn_exp2f((pmx[k] - mx)*LOG2E);
        den = fmaf(lam, ws[PSUM_OFF + (size_t)(k*4 + h)*1024 + n], den);
        num = fmaf(lam, ws[PACC_OFF + (size_t)(k*128 + c)*1024 + n], num);
    }
    ws[AO_OFF + idx] = num * __builtin_amdgcn_rcpf(den);
}

// ---------------- kernel 4: Wo matmul + bias + residual + LayerNorm ------
// grid (64): n-tile of 16. block 256.
__global__ __launch_bounds__(256) void k_final(
    const float* __restrict__ Wo, const float* __restrict__ bo,
    const float* __restrict__ x, const float* __restrict__ gamma,
    const float* __restrict__ beta, const float* __restrict__ ws,
    float* __restrict__ out)
{
    __shared__ float wlds[128*129];
    __shared__ float alds[128*16];
    __shared__ float stats[32];   // mu[16], rstd[16]
    const int t  = threadIdx.x;
    const int n0 = blockIdx.x * 16;

    for (int i = t; i < 16384; i += 256)
        wlds[(i>>7)*129 + (i&127)] = Wo[i];
    const float* AO = ws + AO_OFF;
    for (int i = t; i < 2048; i += 256)
        alds[i] = AO[(size_t)(i>>4)*1024 + n0 + (i&15)];
    __syncthreads();

    const int c = t & 127, ng = t >> 7;
    float acc[8] = {0,0,0,0,0,0,0,0};
    #pragma unroll 4
    for (int k = 0; k < 128; k++){
        const float wv = wlds[c*129 + k];
        const float4 a0 = *(const float4*)&alds[k*16 + ng*8];
        const float4 a1 = *(const float4*)&alds[k*16 + ng*8 + 4];
        acc[0] = fmaf(wv, a0.x, acc[0]);
        acc[1] = fmaf(wv, a0.y, acc[1]);
        acc[2] = fmaf(wv, a0.z, acc[2]);
        acc[3] = fmaf(wv, a0.w, acc[3]);
        acc[4] = fmaf(wv, a1.x, acc[4]);
        acc[5] = fmaf(wv, a1.y, acc[5]);
        acc[6] = fmaf(wv, a1.z, acc[6]);
        acc[7] = fmaf(wv, a1.w, acc[7]);
    }
    const float bov = bo[c];
    #pragma unroll
    for (int i = 0; i < 8; i++)
        acc[i] += bov + x[(size_t)c*1024 + n0 + ng*8 + i];
    __syncthreads();   // done reading alds

    // LN buffer [n16][c128]
    #pragma unroll
    for (int i = 0; i < 8; i++) alds[(ng*8 + i)*128 + c] = acc[i];
    __syncthreads();

    const int w = t >> 6, lane = t & 63;
    for (int r = w*4; r < w*4 + 4; r++){
        const float v0 = alds[r*128 + lane];
        const float v1 = alds[r*128 + 64 + lane];
        const float s = wave_sum64(v0 + v1);
        const float q = wave_sum64(fmaf(v0, v0, v1*v1));
        if (lane == 0){
            const float mu  = s * 0.0078125f;
            const float var = q * 0.0078125f - mu*mu;
            stats[r]      = mu;
            stats[16 + r] = rsqrtf(var + 1e-5f);
        }
    }
    __syncthreads();

    const float g = gamma[c], b = beta[c];
    #pragma unroll
    for (int i = 0; i < 8; i++){
        const int nn = ng*8 + i;
        out[(size_t)c*1024 + n0 + nn] = (acc[i] - stats[nn]) * stats[16 + nn] * g + b;
    }
}

extern "C" void kernel_launch(void* const* d_in, const int* in_sizes, int n_in,
                              void* d_out, int out_size, void* d_ws, size_t ws_size,
                              hipStream_t stream)
{
    const float* x     = (const float*)d_in[0];
    const float* xyz   = (const float*)d_in[1];
    const float* Wq    = (const float*)d_in[2];
    const float* Wk    = (const float*)d_in[3];
    const float* Wv    = (const float*)d_in[4];
    const float* Wp1   = (const float*)d_in[5];
    const float* bp1   = (const float*)d_in[6];
    const float* Wp2   = (const float*)d_in[7];
    const float* bp2   = (const float*)d_in[8];
    const float* Wo    = (const float*)d_in[9];
    const float* bo    = (const float*)d_in[10];
    const float* gamma = (const float*)d_in[11];
    const float* beta  = (const float*)d_in[12];
    float* ws  = (float*)d_ws;
    float* out = (float*)d_out;

    hipLaunchKernelGGL(k_prep,    dim3(64, 4),  dim3(256), 0, stream,
                       x, xyz, Wq, Wk, Wv, Wp1, ws);
    hipLaunchKernelGGL(k_prep2,   dim3(64),     dim3(256), 0, stream,
                       Wp2, bp2, bp1, ws);
    hipLaunchKernelGGL(k_attn,    dim3(128, 8), dim3(256), 0, stream,
                       ws, ws);
    hipLaunchKernelGGL(k_combine, dim3(512),    dim3(256), 0, stream, ws);
    hipLaunchKernelGGL(k_final,   dim3(64),     dim3(256), 0, stream,
                       Wo, bo, x, gamma, beta, ws, out);
}

// Round 4
// 54.351 us; speedup vs baseline: 2.2725x; 1.5728x over previous
//
#include <hip/hip_runtime.h>

#define LOG2E 1.44269504088896340736f
#define C2G   0.39894228040143267794f   // 1/sqrt(2*pi)
#define K2M  -0.79788456080286535588f   // -2*C2G

// ---------------- workspace layout (float offsets) ----------------
static constexpr size_t Q_OFF    = 0;          // [128][1024] Q / sqrt(D)
static constexpr size_t K_OFF    = 131072;     // [128][1024]
static constexpr size_t VT_OFF   = 262144;     // [1024][128]  V transposed
static constexpr size_t PACC_OFF = 393216;     // [8][1024][128] partial PV ([chunk][n][c])
static constexpr size_t PMAX_OFF = 1441792;    // [8][4][1024]
static constexpr size_t PSUM_OFF = 1474560;    // [8][4][1024]
static constexpr size_t ROWT_OFF = 1507328;    // [4][1024]
static constexpr size_t COLT_OFF = 1511424;    // [4][1024]
static constexpr size_t KG_OFF   = 1515520;    // [4][3][1024]  K2M * (M_h · xyz[n])
// total = 1,527,808 floats = 5.83 MB

__device__ __forceinline__ float wave_max64(float v){
    #pragma unroll
    for (int m = 32; m >= 1; m >>= 1) v = fmaxf(v, __shfl_xor(v, m, 64));
    return v;
}
__device__ __forceinline__ float wave_sum64(float v){
    #pragma unroll
    for (int m = 32; m >= 1; m >>= 1) v += __shfl_xor(v, m, 64);
    return v;
}

// ---------------- kernel 1: projections + pos-bias precompute ----------
// grid (64, 4): x = n-tile of 16, y = mat (0=Q,1=K,2=V,3=pos terms)
__global__ __launch_bounds__(256) void k_prep(
    const float* __restrict__ x, const float* __restrict__ xyz,
    const float* __restrict__ Wq, const float* __restrict__ Wk,
    const float* __restrict__ Wv, const float* __restrict__ Wp1,
    const float* __restrict__ bp1, const float* __restrict__ Wp2,
    const float* __restrict__ bp2, float* __restrict__ ws)
{
    __shared__ float wlds[128*129];   // [c][k] pitch 129 -> conflict-free
    __shared__ float xlds[128*16];    // [k][n16]
    const int t   = threadIdx.x;
    const int mat = blockIdx.y;
    const int n0  = blockIdx.x * 16;

    if (mat == 3){
        // carve mat-3 scratch out of wlds
        float* wb   = wlds;               // [4][128]
        float* pt   = wlds + 512;         // [128][17] pitch 17
        float* Msh  = wlds + 512 + 2176;  // [4][9]
        float* bbar = Msh + 36;           // [4]

        for (int idx = t; idx < 512; idx += 256){
            const int h = idx >> 7, c = idx & 127;
            float s = 0.f;
            #pragma unroll 8
            for (int d = 0; d < 32; d++) s += Wp2[(size_t)(h*32+d)*128 + c];
            wb[idx] = s * 0.03125f;
        }
        if (t < 4){
            float s = 0.f;
            #pragma unroll 8
            for (int d = 0; d < 32; d++) s += bp2[t*32+d];
            bbar[t] = s * 0.03125f;
        }
        {   // p-tile: p[c, n0..n0+15]
            const int c = t & 127, ng = t >> 7;
            const float w0 = Wp1[c*3], w1 = Wp1[c*3+1], w2 = Wp1[c*3+2];
            #pragma unroll
            for (int i = 0; i < 8; i++){
                const int nn = ng*8 + i, n = n0 + nn;
                pt[c*17 + nn] = w0*xyz[n*3] + w1*xyz[n*3+1] + w2*xyz[n*3+2];
            }
        }
        __syncthreads();

        if (t < 36){   // M_h[a][b] = sum_c wbar * Wp1[c,a] * Wp1[c,b]
            const int h = t / 9, ab = t % 9, a = ab / 3, b = ab % 3;
            float m = 0.f;
            for (int c = 0; c < 128; c++)
                m += wb[h*128+c] * Wp1[c*3+a] * Wp1[c*3+b];
            Msh[t] = m;
        }
        __syncthreads();

        if (t < 64){   // ROWT / COLT
            const int h = t >> 4, nn = t & 15;
            float ra = 0.f, ca = 0.f;
            for (int c = 0; c < 128; c++){
                const float w  = wb[h*128+c];
                const float p  = pt[c*17+nn];
                const float b1 = bp1[c];
                const float a  = fmaf(2.f*C2G, b1, 0.5f);
                const float p2 = C2G*p*p;
                ra += w * (a*p + p2 + 0.5f*b1 + C2G*b1*b1);
                ca += w * (p2 - a*p);
            }
            ws[ROWT_OFF + (size_t)h*1024 + n0+nn] = ra + bbar[h];
            ws[COLT_OFF + (size_t)h*1024 + n0+nn] = ca;
        } else if (t < 64 + 192){   // KG[h][a][n] = K2M * (M_h · xyz[n])[a]
            const int u = t - 64;
            const int nn = u & 15, ha = u >> 4, h = ha / 3, a = ha % 3;
            const int n = n0 + nn;
            const float g = Msh[h*9+a*3+0]*xyz[n*3+0]
                          + Msh[h*9+a*3+1]*xyz[n*3+1]
                          + Msh[h*9+a*3+2]*xyz[n*3+2];
            ws[KG_OFF + (size_t)(h*3+a)*1024 + n] = K2M * g;
        }
        return;
    }

    const float* W = (mat == 0) ? Wq : (mat == 1 ? Wk : Wv);
    for (int i = t; i < 16384; i += 256)
        wlds[(i>>7)*129 + (i&127)] = W[i];
    for (int i = t; i < 2048; i += 256)
        xlds[i] = x[(size_t)(i>>4)*1024 + n0 + (i&15)];
    __syncthreads();

    const int c = t & 127, ng = t >> 7;
    float acc[8] = {0,0,0,0,0,0,0,0};
    #pragma unroll 4
    for (int k = 0; k < 128; k++){
        const float wv = wlds[c*129 + k];
        const float4 a0 = *(const float4*)&xlds[k*16 + ng*8];
        const float4 a1 = *(const float4*)&xlds[k*16 + ng*8 + 4];
        acc[0] = fmaf(wv, a0.x, acc[0]);
        acc[1] = fmaf(wv, a0.y, acc[1]);
        acc[2] = fmaf(wv, a0.z, acc[2]);
        acc[3] = fmaf(wv, a0.w, acc[3]);
        acc[4] = fmaf(wv, a1.x, acc[4]);
        acc[5] = fmaf(wv, a1.y, acc[5]);
        acc[6] = fmaf(wv, a1.z, acc[6]);
        acc[7] = fmaf(wv, a1.w, acc[7]);
    }

    if (mat == 0){
        #pragma unroll
        for (int i = 0; i < 8; i++) acc[i] *= 0.17677669529663689f; // 1/sqrt(32)
        float4* dst = (float4*)&ws[Q_OFF + (size_t)c*1024 + n0 + ng*8];
        dst[0] = make_float4(acc[0],acc[1],acc[2],acc[3]);
        dst[1] = make_float4(acc[4],acc[5],acc[6],acc[7]);
    } else if (mat == 1){
        float4* dst = (float4*)&ws[K_OFF + (size_t)c*1024 + n0 + ng*8];
        dst[0] = make_float4(acc[0],acc[1],acc[2],acc[3]);
        dst[1] = make_float4(acc[4],acc[5],acc[6],acc[7]);
    } else {
        #pragma unroll
        for (int i = 0; i < 8; i++){
            const int n = n0 + ng*8 + i;
            ws[VT_OFF + (size_t)n*128 + c] = acc[i];   // V transposed
        }
    }
}

// ---------------- kernel 2: scores + chunk softmax + partial PV ----------
// grid (128, 8): x = n-tile of 8, y = m-chunk of 128. block 256 (4 waves).
// Wave w owns n = bx*8 + w*2 + {0,1}; lane owns m = by*128 + 2*lane + {0,1}.
__global__ __launch_bounds__(256) void k_attn(
    const float* __restrict__ xyz, const float* __restrict__ ws_c,
    float* __restrict__ ws)
{
    __shared__ float slds[32*128];   // [4h*8n][128m] scores -> exp

    const int t    = threadIdx.x;
    const int lane = t & 63, w = t >> 6;
    const int bx   = blockIdx.x, by = blockIdx.y;
    const int nb   = __builtin_amdgcn_readfirstlane(bx*8 + w*2);
    const int m0   = by*128 + 2*lane;

    const float* Qp = ws_c + Q_OFF;
    const float* Kp = ws_c + K_OFF;

    // xyz for m0, m0+1 (6 consecutive floats)
    const float2 xa = *(const float2*)(xyz + (size_t)m0*3);      // x0,y0
    const float2 xb = *(const float2*)(xyz + (size_t)m0*3 + 2);  // z0,x1
    const float2 xc = *(const float2*)(xyz + (size_t)m0*3 + 4);  // y1,z1

    float acc[2][2][4];
    // rank-3 cross term init: acc = KG[h][:, n] · xyz[m]
    #pragma unroll
    for (int h = 0; h < 4; h++){
        float kg0[3], kg1[3];
        #pragma unroll
        for (int a = 0; a < 3; a++){
            kg0[a] = ws_c[KG_OFF + (size_t)(h*3+a)*1024 + nb];
            kg1[a] = ws_c[KG_OFF + (size_t)(h*3+a)*1024 + nb + 1];
        }
        acc[0][0][h] = kg0[0]*xa.x + kg0[1]*xa.y + kg0[2]*xb.x;
        acc[0][1][h] = kg0[0]*xb.y + kg0[1]*xc.x + kg0[2]*xc.y;
        acc[1][0][h] = kg1[0]*xa.x + kg1[1]*xa.y + kg1[2]*xb.x;
        acc[1][1][h] = kg1[0]*xb.y + kg1[1]*xc.x + kg1[2]*xc.y;
    }

    // QK^T (Q already has 1/sqrt(D))
    #pragma unroll
    for (int h = 0; h < 4; h++){
        #pragma unroll 8
        for (int d = 0; d < 32; d++){
            const size_t r = (size_t)(h*32 + d)*1024;
            const float2 k2 = *(const float2*)(Kp + r + m0);
            const float2 q2 = *(const float2*)(Qp + r + nb);   // uniform
            acc[0][0][h] = fmaf(q2.x, k2.x, acc[0][0][h]);
            acc[0][1][h] = fmaf(q2.x, k2.y, acc[0][1][h]);
            acc[1][0][h] = fmaf(q2.y, k2.x, acc[1][0][h]);
            acc[1][1][h] = fmaf(q2.y, k2.y, acc[1][1][h]);
        }
    }

    // affine terms + write scores
    #pragma unroll
    for (int h = 0; h < 4; h++){
        const float  rt0 = ws_c[ROWT_OFF + (size_t)h*1024 + nb];
        const float  rt1 = ws_c[ROWT_OFF + (size_t)h*1024 + nb + 1];
        const float2 ct  = *(const float2*)(ws_c + COLT_OFF + (size_t)h*1024 + m0);
        const int r0 = (h*8 + w*2)*128;
        *(float2*)&slds[r0 + 2*lane] =
            make_float2(acc[0][0][h]+rt0+ct.x, acc[0][1][h]+rt0+ct.y);
        *(float2*)&slds[r0 + 128 + 2*lane] =
            make_float2(acc[1][0][h]+rt1+ct.x, acc[1][1][h]+rt1+ct.y);
    }
    __syncthreads();

    // per-chunk softmax partials; wave w owns rows [w*8, w*8+8)
    for (int r = w*8; r < w*8 + 8; r++){
        const float v0 = slds[r*128 + lane];
        const float v1 = slds[r*128 + 64 + lane];
        const float mx = wave_max64(fmaxf(v0, v1));
        const float e0 = __builtin_amdgcn_exp2f((v0 - mx)*LOG2E);
        const float e1 = __builtin_amdgcn_exp2f((v1 - mx)*LOG2E);
        slds[r*128 + lane]      = e0;
        slds[r*128 + 64 + lane] = e1;
        const float sm = wave_sum64(e0 + e1);
        if (lane == 0){
            const int h = r >> 3, i = r & 7;
            ws[PMAX_OFF + (size_t)(by*4 + h)*1024 + bx*8 + i] = mx;
            ws[PSUM_OFF + (size_t)(by*4 + h)*1024 + bx*8 + i] = sm;
        }
    }
    __syncthreads();

    // partial PV: pacc[chunk][n][c] = sum_m e[h(c)][n][m] * V[c][m]
    const int c = t & 127, ng = t >> 7;
    const int h = c >> 5;
    const float* Vt = ws_c + VT_OFF + (size_t)by*128*128;
    float pv[4] = {0,0,0,0};
    #pragma unroll 1
    for (int m = 0; m < 128; m += 4){
        const float v0 = Vt[(size_t)(m+0)*128 + c];
        const float v1 = Vt[(size_t)(m+1)*128 + c];
        const float v2 = Vt[(size_t)(m+2)*128 + c];
        const float v3 = Vt[(size_t)(m+3)*128 + c];
        #pragma unroll
        for (int i = 0; i < 4; i++){
            const float4 e4 = *(const float4*)&slds[(h*8 + ng*4 + i)*128 + m];
            pv[i] = fmaf(e4.x, v0, pv[i]);
            pv[i] = fmaf(e4.y, v1, pv[i]);
            pv[i] = fmaf(e4.z, v2, pv[i]);
            pv[i] = fmaf(e4.w, v3, pv[i]);
        }
    }
    #pragma unroll
    for (int i = 0; i < 4; i++)
        ws[PACC_OFF + (size_t)(by*1024 + bx*8 + ng*4 + i)*128 + c] = pv[i];
}

// ---------------- kernel 3: combine + Wo matmul + residual + LayerNorm ---
// grid (256): n-tile of 4. block 256.
__global__ __launch_bounds__(256) void k_final(
    const float* __restrict__ Wo, const float* __restrict__ bo,
    const float* __restrict__ x, const float* __restrict__ gamma,
    const float* __restrict__ beta, const float* __restrict__ ws,
    float* __restrict__ out)
{
    __shared__ float wlds[128*129];
    __shared__ float alds[128*4];     // [k][nn] then reused as [nn][c]
    __shared__ float wcomb[8*16];     // [chunk][h*4+nn]
    __shared__ float stats[8];        // mu[4], rstd[4]
    const int t  = threadIdx.x;
    const int n0 = blockIdx.x * 4;

    for (int i = t; i < 4096; i += 256){
        const float4 wv = *(const float4*)(Wo + (size_t)i*4);
        const int cc = (i*4) >> 7, kk = (i*4) & 127;
        wlds[cc*129 + kk + 0] = wv.x;
        wlds[cc*129 + kk + 1] = wv.y;
        wlds[cc*129 + kk + 2] = wv.z;
        wlds[cc*129 + kk + 3] = wv.w;
    }
    if (t < 16){   // combine weights per (h, nn)
        const int h = t >> 2, nn = t & 3;
        float pm[8]; float mx = -3.4e38f;
        #pragma unroll
        for (int k = 0; k < 8; k++){
            pm[k] = ws[PMAX_OFF + (size_t)(k*4 + h)*1024 + n0 + nn];
            mx = fmaxf(mx, pm[k]);
        }
        float lam[8]; float den = 0.f;
        #pragma unroll
        for (int k = 0; k < 8; k++){
            lam[k] = __builtin_amdgcn_exp2f((pm[k] - mx)*LOG2E);
            den = fmaf(lam[k], ws[PSUM_OFF + (size_t)(k*4 + h)*1024 + n0 + nn], den);
        }
        const float rd = __builtin_amdgcn_rcpf(den);
        #pragma unroll
        for (int k = 0; k < 8; k++) wcomb[k*16 + t] = lam[k]*rd;
    }
    __syncthreads();

    const int c = t & 127, ng = t >> 7, h = c >> 5;
    {   // combine PACC -> alds[k-channel][nn]
        #pragma unroll
        for (int j = 0; j < 2; j++){
            const int nn = ng*2 + j;
            float num = 0.f;
            #pragma unroll
            for (int k = 0; k < 8; k++)
                num = fmaf(wcomb[k*16 + h*4 + nn],
                           ws[PACC_OFF + (size_t)(k*1024 + n0 + nn)*128 + c], num);
            alds[c*4 + nn] = num;
        }
    }
    __syncthreads();

    float acc2[2] = {0.f, 0.f};
    #pragma unroll 4
    for (int k = 0; k < 128; k++){
        const float  wv = wlds[c*129 + k];
        const float2 a2 = *(const float2*)&alds[k*4 + ng*2];
        acc2[0] = fmaf(wv, a2.x, acc2[0]);
        acc2[1] = fmaf(wv, a2.y, acc2[1]);
    }
    const float  bov = bo[c];
    const float2 xr  = *(const float2*)(x + (size_t)c*1024 + n0 + ng*2);
    acc2[0] += bov + xr.x;
    acc2[1] += bov + xr.y;
    __syncthreads();   // done reading alds

    alds[(ng*2 + 0)*128 + c] = acc2[0];
    alds[(ng*2 + 1)*128 + c] = acc2[1];
    __syncthreads();

    {   // LN stats: wave w owns row w
        const int lane = t & 63, w = t >> 6;
        const float v0 = alds[w*128 + lane];
        const float v1 = alds[w*128 + 64 + lane];
        const float s = wave_sum64(v0 + v1);
        const float q = wave_sum64(fmaf(v0, v0, v1*v1));
        if (lane == 0){
            const float mu  = s * 0.0078125f;
            const float var = q * 0.0078125f - mu*mu;
            stats[w]     = mu;
            stats[4 + w] = rsqrtf(var + 1e-5f);
        }
    }
    __syncthreads();

    const float g = gamma[c], b = beta[c];
    const int nn0 = ng*2;
    float2 o2;
    o2.x = (acc2[0] - stats[nn0])  * stats[4 + nn0]  * g + b;
    o2.y = (acc2[1] - stats[nn0+1])* stats[4 + nn0+1]* g + b;
    *(float2*)(out + (size_t)c*1024 + n0 + nn0) = o2;
}

extern "C" void kernel_launch(void* const* d_in, const int* in_sizes, int n_in,
                              void* d_out, int out_size, void* d_ws, size_t ws_size,
                              hipStream_t stream)
{
    const float* x     = (const float*)d_in[0];
    const float* xyz   = (const float*)d_in[1];
    const float* Wq    = (const float*)d_in[2];
    const float* Wk    = (const float*)d_in[3];
    const float* Wv    = (const float*)d_in[4];
    const float* Wp1   = (const float*)d_in[5];
    const float* bp1   = (const float*)d_in[6];
    const float* Wp2   = (const float*)d_in[7];
    const float* bp2   = (const float*)d_in[8];
    const float* Wo    = (const float*)d_in[9];
    const float* bo    = (const float*)d_in[10];
    const float* gamma = (const float*)d_in[11];
    const float* beta  = (const float*)d_in[12];
    float* ws  = (float*)d_ws;
    float* out = (float*)d_out;

    hipLaunchKernelGGL(k_prep,  dim3(64, 4),  dim3(256), 0, stream,
                       x, xyz, Wq, Wk, Wv, Wp1, bp1, Wp2, bp2, ws);
    hipLaunchKernelGGL(k_attn,  dim3(128, 8), dim3(256), 0, stream,
                       xyz, ws, ws);
    hipLaunchKernelGGL(k_final, dim3(256),    dim3(256), 0, stream,
                       Wo, bo, x, gamma, beta, ws, out);
}

// Round 5
// 38.653 us; speedup vs baseline: 3.1955x; 1.4061x over previous
//
#include <hip/hip_runtime.h>

#define LOG2E 1.44269504088896340736f
#define C2G   0.39894228040143267794f   // 1/sqrt(2*pi)
#define K2M  -0.79788456080286535588f   // -2*C2G

typedef __attribute__((ext_vector_type(4))) float f32x4;
typedef __attribute__((ext_vector_type(8))) short s16x8;

// ---------------- workspace layout (float offsets) ----------------
// Raw Q/K/V are dead after k_frag; PACC overlays them.
static constexpr size_t QR_OFF   = 0;          // [128][1024] Q / sqrt(D)   (phase 1)
static constexpr size_t KR_OFF   = 131072;     // [128][1024]               (phase 1)
static constexpr size_t VT_OFF   = 262144;     // [1024][128] V^T           (phase 1)
static constexpr size_t PACC_OFF = 0;          // [8][1024][128] partial PV (phase 2, overlays)
static constexpr size_t PMAX_OFF = 1048576;    // [8][4][1024]
static constexpr size_t PSUM_OFF = 1081344;    // [8][4][1024]
static constexpr size_t ROWT_OFF = 1114112;    // [4][1024]
static constexpr size_t COLT_OFF = 1118208;    // [4][1024]
static constexpr size_t KG_OFF   = 1122304;    // [4][3][1024]  K2M * (M_h · xyz[n])
static constexpr size_t QF_OFF   = 1134592;    // bf16 [4h][64nt][2s][64l][8j] = 524288 bf16
static constexpr size_t KF_OFF   = 1396736;    // bf16 same shape (m-tiles)
static constexpr size_t VF_OFF   = 1658880;    // bf16 [32ks][8tc][64l][8j]  = 131072 bf16
// total = 1,724,416 floats = 6.58 MB

__device__ __forceinline__ unsigned short f2bf(float f){
    unsigned int u = __builtin_bit_cast(unsigned int, f);
    u += 0x7fffu + ((u >> 16) & 1u);          // RNE (no NaNs in this data)
    return (unsigned short)(u >> 16);
}

__device__ __forceinline__ float wave_sum64(float v){
    #pragma unroll
    for (int m = 32; m >= 1; m >>= 1) v += __shfl_xor(v, m, 64);
    return v;
}

// ---------------- kernel 1: projections + pos-bias precompute ----------
// grid (64, 4): x = n-tile of 16, y = mat (0=Q,1=K,2=V,3=pos terms)
__global__ __launch_bounds__(256) void k_prep(
    const float* __restrict__ x, const float* __restrict__ xyz,
    const float* __restrict__ Wq, const float* __restrict__ Wk,
    const float* __restrict__ Wv, const float* __restrict__ Wp1,
    const float* __restrict__ bp1, const float* __restrict__ Wp2,
    const float* __restrict__ bp2, float* __restrict__ ws)
{
    __shared__ float wlds[128*129];   // [c][k] pitch 129 -> conflict-free
    __shared__ float xlds[128*16];    // [k][n16]
    const int t   = threadIdx.x;
    const int mat = blockIdx.y;
    const int n0  = blockIdx.x * 16;

    if (mat == 3){
        // carve mat-3 scratch out of wlds
        float* wb   = wlds;               // [4][128]
        float* pt   = wlds + 512;         // [128][17] pitch 17
        float* Msh  = wlds + 512 + 2176;  // [4][9]
        float* bbar = Msh + 36;           // [4]

        for (int idx = t; idx < 512; idx += 256){
            const int h = idx >> 7, c = idx & 127;
            float s = 0.f;
            #pragma unroll 8
            for (int d = 0; d < 32; d++) s += Wp2[(size_t)(h*32+d)*128 + c];
            wb[idx] = s * 0.03125f;
        }
        if (t < 4){
            float s = 0.f;
            #pragma unroll 8
            for (int d = 0; d < 32; d++) s += bp2[t*32+d];
            bbar[t] = s * 0.03125f;
        }
        {   // p-tile: p[c, n0..n0+15]
            const int c = t & 127, ng = t >> 7;
            const float w0 = Wp1[c*3], w1 = Wp1[c*3+1], w2 = Wp1[c*3+2];
            #pragma unroll
            for (int i = 0; i < 8; i++){
                const int nn = ng*8 + i, n = n0 + nn;
                pt[c*17 + nn] = w0*xyz[n*3] + w1*xyz[n*3+1] + w2*xyz[n*3+2];
            }
        }
        __syncthreads();

        if (t < 36){   // M_h[a][b] = sum_c wbar * Wp1[c,a] * Wp1[c,b]
            const int h = t / 9, ab = t % 9, a = ab / 3, b = ab % 3;
            float m = 0.f;
            for (int c = 0; c < 128; c++)
                m += wb[h*128+c] * Wp1[c*3+a] * Wp1[c*3+b];
            Msh[t] = m;
        }
        __syncthreads();

        if (t < 64){   // ROWT / COLT
            const int h = t >> 4, nn = t & 15;
            float ra = 0.f, ca = 0.f;
            for (int c = 0; c < 128; c++){
                const float w  = wb[h*128+c];
                const float p  = pt[c*17+nn];
                const float b1 = bp1[c];
                const float a  = fmaf(2.f*C2G, b1, 0.5f);
                const float p2 = C2G*p*p;
                ra += w * (a*p + p2 + 0.5f*b1 + C2G*b1*b1);
                ca += w * (p2 - a*p);
            }
            ws[ROWT_OFF + (size_t)h*1024 + n0+nn] = ra + bbar[h];
            ws[COLT_OFF + (size_t)h*1024 + n0+nn] = ca;
        } else if (t < 64 + 192){   // KG[h][a][n] = K2M * (M_h · xyz[n])[a]
            const int u = t - 64;
            const int nn = u & 15, ha = u >> 4, h = ha / 3, a = ha % 3;
            const int n = n0 + nn;
            const float g = Msh[h*9+a*3+0]*xyz[n*3+0]
                          + Msh[h*9+a*3+1]*xyz[n*3+1]
                          + Msh[h*9+a*3+2]*xyz[n*3+2];
            ws[KG_OFF + (size_t)(h*3+a)*1024 + n] = K2M * g;
        }
        return;
    }

    const float* W = (mat == 0) ? Wq : (mat == 1 ? Wk : Wv);
    for (int i = t; i < 16384; i += 256)
        wlds[(i>>7)*129 + (i&127)] = W[i];
    for (int i = t; i < 2048; i += 256)
        xlds[i] = x[(size_t)(i>>4)*1024 + n0 + (i&15)];
    __syncthreads();

    const int c = t & 127, ng = t >> 7;
    float acc[8] = {0,0,0,0,0,0,0,0};
    #pragma unroll 4
    for (int k = 0; k < 128; k++){
        const float wv = wlds[c*129 + k];
        const float4 a0 = *(const float4*)&xlds[k*16 + ng*8];
        const float4 a1 = *(const float4*)&xlds[k*16 + ng*8 + 4];
        acc[0] = fmaf(wv, a0.x, acc[0]);
        acc[1] = fmaf(wv, a0.y, acc[1]);
        acc[2] = fmaf(wv, a0.z, acc[2]);
        acc[3] = fmaf(wv, a0.w, acc[3]);
        acc[4] = fmaf(wv, a1.x, acc[4]);
        acc[5] = fmaf(wv, a1.y, acc[5]);
        acc[6] = fmaf(wv, a1.z, acc[6]);
        acc[7] = fmaf(wv, a1.w, acc[7]);
    }

    if (mat == 0){
        #pragma unroll
        for (int i = 0; i < 8; i++) acc[i] *= 0.17677669529663689f; // 1/sqrt(32)
        float4* dst = (float4*)&ws[QR_OFF + (size_t)c*1024 + n0 + ng*8];
        dst[0] = make_float4(acc[0],acc[1],acc[2],acc[3]);
        dst[1] = make_float4(acc[4],acc[5],acc[6],acc[7]);
    } else if (mat == 1){
        float4* dst = (float4*)&ws[KR_OFF + (size_t)c*1024 + n0 + ng*8];
        dst[0] = make_float4(acc[0],acc[1],acc[2],acc[3]);
        dst[1] = make_float4(acc[4],acc[5],acc[6],acc[7]);
    } else {
        #pragma unroll
        for (int i = 0; i < 8; i++){
            const int n = n0 + ng*8 + i;
            ws[VT_OFF + (size_t)n*128 + c] = acc[i];   // V transposed
        }
    }
}

// ---------------- kernel 1b: build bf16 MFMA fragments ----------------
// 1280 wave-slots: QF[0,512) KF[512,1024) VF[1024,1280). grid(320) x 256.
// Shared k-bijections: scores g(l,j)=(l>>4)*8+j; PV f(l,j)=(l>>4)*4+(j&3)+16*(j>>2).
__global__ __launch_bounds__(256) void k_frag(
    const float* __restrict__ xyz, float* __restrict__ ws)
{
    const int t = threadIdx.x, l = t & 63, g = l >> 4;
    const int slot = blockIdx.x*4 + (t >> 6);
    s16x8 v;

    if (slot < 1024){
        const bool isQ = slot < 512;
        const int s2 = isQ ? slot : slot - 512;
        const int h = s2 >> 7, nt = (s2 & 127) >> 1, s = s2 & 1;
        const int n = nt*16 + (l & 15);
        if (s == 0){
            const float* R = ws + (isQ ? QR_OFF : KR_OFF);
            #pragma unroll
            for (int j = 0; j < 8; j++)
                v[j] = (short)f2bf(R[(size_t)(h*32 + g*8 + j)*1024 + n]);
        } else {
            #pragma unroll
            for (int j = 0; j < 8; j++){
                const int dd = g*8 + j;
                float f;
                if (isQ)
                    f = (dd < 3)  ? ws[KG_OFF + (size_t)(h*3+dd)*1024 + n]
                      : (dd == 3) ? ws[ROWT_OFF + (size_t)h*1024 + n]
                      : (dd == 4) ? 1.0f : 0.0f;
                else
                    f = (dd < 3)  ? xyz[(size_t)n*3 + dd]
                      : (dd == 3) ? 1.0f
                      : (dd == 4) ? ws[COLT_OFF + (size_t)h*1024 + n] : 0.0f;
                v[j] = (short)f2bf(f);
            }
        }
        ((s16x8*)(ws + (isQ ? QF_OFF : KF_OFF)))[(size_t)s2*64 + l] = v;
    } else {
        const int vs = slot - 1024;          // 0..255
        const int ks = vs >> 3, tc = vs & 7;
        const int c  = tc*16 + (l & 15);
        #pragma unroll
        for (int j = 0; j < 8; j++){
            const int m = ks*32 + g*4 + (j & 3) + ((j >> 2) << 4);
            v[j] = (short)f2bf(ws[VT_OFF + (size_t)m*128 + c]);
        }
        ((s16x8*)(ws + VF_OFF))[(size_t)vs*64 + l] = v;
    }
}

// ---------------- kernel 2: MFMA scores + chunk softmax + MFMA PV --------
// grid (64, 8): x = n-tile of 16, y = m-chunk of 128. block 256 = 4 waves,
// wave = head. No LDS, no __syncthreads.
// S^T tile: A=K-frag (rows m), B=Q-frag (cols n); D: m=(l>>4)*4+reg, n=l&15.
// P then feeds PV's B operand DIRECTLY from registers (f-mapping matches).
__global__ __launch_bounds__(256) void k_attn(
    const float* __restrict__ ws_c, float* __restrict__ ws)
{
    const int t = threadIdx.x, l = t & 63, h = t >> 6;
    const int bx = blockIdx.x, by = blockIdx.y;

    const s16x8* QFv = (const s16x8*)(ws_c + QF_OFF);
    const s16x8* KFv = (const s16x8*)(ws_c + KF_OFF);
    const s16x8* VFv = (const s16x8*)(ws_c + VF_OFF);

    const s16x8 bq0 = QFv[(size_t)(h*128 + bx*2 + 0)*64 + l];
    const s16x8 bq1 = QFv[(size_t)(h*128 + bx*2 + 1)*64 + l];

    // scores: 8 m-tiles, K=32 (real d) + K=32 (bias dims)
    f32x4 sc[8];
    #pragma unroll
    for (int tt = 0; tt < 8; tt++){
        const int mt = by*8 + tt;
        const s16x8 ak0 = KFv[(size_t)(h*128 + mt*2 + 0)*64 + l];
        const s16x8 ak1 = KFv[(size_t)(h*128 + mt*2 + 1)*64 + l];
        f32x4 c = {0.f, 0.f, 0.f, 0.f};
        c = __builtin_amdgcn_mfma_f32_16x16x32_bf16(ak0, bq0, c, 0, 0, 0);
        c = __builtin_amdgcn_mfma_f32_16x16x32_bf16(ak1, bq1, c, 0, 0, 0);
        sc[tt] = c;
    }

    // chunk softmax over m (in-lane 32 + lanes l^16, l^32)
    float mx = -3.4e38f;
    #pragma unroll
    for (int tt = 0; tt < 8; tt++)
        #pragma unroll
        for (int r = 0; r < 4; r++) mx = fmaxf(mx, sc[tt][r]);
    mx = fmaxf(mx, __shfl_xor(mx, 16, 64));
    mx = fmaxf(mx, __shfl_xor(mx, 32, 64));

    float p[8][4];
    float sum = 0.f;
    #pragma unroll
    for (int tt = 0; tt < 8; tt++)
        #pragma unroll
        for (int r = 0; r < 4; r++){
            const float e = __builtin_amdgcn_exp2f((sc[tt][r] - mx)*LOG2E);
            p[tt][r] = e;
            sum += e;
        }
    sum += __shfl_xor(sum, 16, 64);
    sum += __shfl_xor(sum, 32, 64);

    if (l < 16){
        ws[PMAX_OFF + (size_t)(by*4 + h)*1024 + bx*16 + l] = mx;
        ws[PSUM_OFF + (size_t)(by*4 + h)*1024 + bx*16 + l] = sum;
    }

    // pack P as PV B-fragments: step s uses tiles {2s, 2s+1}, regs 0..3
    s16x8 pb[4];
    #pragma unroll
    for (int s = 0; s < 4; s++){
        s16x8 b;
        b[0] = (short)f2bf(p[2*s][0]);
        b[1] = (short)f2bf(p[2*s][1]);
        b[2] = (short)f2bf(p[2*s][2]);
        b[3] = (short)f2bf(p[2*s][3]);
        b[4] = (short)f2bf(p[2*s+1][0]);
        b[5] = (short)f2bf(p[2*s+1][1]);
        b[6] = (short)f2bf(p[2*s+1][2]);
        b[7] = (short)f2bf(p[2*s+1][3]);
        pb[s] = b;
    }

    // PV: D[c][n] = sum_m V[c][m] * P[m][n]; A=V-frag, B=pb (in-register)
    #pragma unroll
    for (int tc = 0; tc < 8; tc++){
        f32x4 o = {0.f, 0.f, 0.f, 0.f};
        #pragma unroll
        for (int s = 0; s < 4; s++){
            const s16x8 av = VFv[(size_t)((by*4 + s)*8 + tc)*64 + l];
            o = __builtin_amdgcn_mfma_f32_16x16x32_bf16(av, pb[s], o, 0, 0, 0);
        }
        *(f32x4*)&ws[PACC_OFF + (size_t)(by*1024 + bx*16 + (l & 15))*128
                     + tc*16 + (l >> 4)*4] = o;
    }
}

// ---------------- kernel 3: combine + Wo matmul + residual + LayerNorm ---
// grid (256): n-tile of 4. block 256.
__global__ __launch_bounds__(256) void k_final(
    const float* __restrict__ Wo, const float* __restrict__ bo,
    const float* __restrict__ x, const float* __restrict__ gamma,
    const float* __restrict__ beta, const float* __restrict__ ws,
    float* __restrict__ out)
{
    __shared__ float wlds[128*129];
    __shared__ float alds[128*4];     // [k][nn] then reused as [nn][c]
    __shared__ float wcomb[8*16];     // [chunk][h*4+nn]
    __shared__ float stats[8];        // mu[4], rstd[4]
    const int t  = threadIdx.x;
    const int n0 = blockIdx.x * 4;

    for (int i = t; i < 4096; i += 256){
        const float4 wv = *(const float4*)(Wo + (size_t)i*4);
        const int cc = (i*4) >> 7, kk = (i*4) & 127;
        wlds[cc*129 + kk + 0] = wv.x;
        wlds[cc*129 + kk + 1] = wv.y;
        wlds[cc*129 + kk + 2] = wv.z;
        wlds[cc*129 + kk + 3] = wv.w;
    }
    if (t < 16){   // combine weights per (h, nn)
        const int h = t >> 2, nn = t & 3;
        float pm[8]; float mx = -3.4e38f;
        #pragma unroll
        for (int k = 0; k < 8; k++){
            pm[k] = ws[PMAX_OFF + (size_t)(k*4 + h)*1024 + n0 + nn];
            mx = fmaxf(mx, pm[k]);
        }
        float lam[8]; float den = 0.f;
        #pragma unroll
        for (int k = 0; k < 8; k++){
            lam[k] = __builtin_amdgcn_exp2f((pm[k] - mx)*LOG2E);
            den = fmaf(lam[k], ws[PSUM_OFF + (size_t)(k*4 + h)*1024 + n0 + nn], den);
        }
        const float rd = __builtin_amdgcn_rcpf(den);
        #pragma unroll
        for (int k = 0; k < 8; k++) wcomb[k*16 + t] = lam[k]*rd;
    }
    __syncthreads();

    const int c = t & 127, ng = t >> 7, h = c >> 5;
    {   // combine PACC -> alds[k-channel][nn]
        #pragma unroll
        for (int j = 0; j < 2; j++){
            const int nn = ng*2 + j;
            float num = 0.f;
            #pragma unroll
            for (int k = 0; k < 8; k++)
                num = fmaf(wcomb[k*16 + h*4 + nn],
                           ws[PACC_OFF + (size_t)(k*1024 + n0 + nn)*128 + c], num);
            alds[c*4 + nn] = num;
        }
    }
    __syncthreads();

    float acc2[2] = {0.f, 0.f};
    #pragma unroll 4
    for (int k = 0; k < 128; k++){
        const float  wv = wlds[c*129 + k];
        const float2 a2 = *(const float2*)&alds[k*4 + ng*2];
        acc2[0] = fmaf(wv, a2.x, acc2[0]);
        acc2[1] = fmaf(wv, a2.y, acc2[1]);
    }
    const float  bov = bo[c];
    const float2 xr  = *(const float2*)(x + (size_t)c*1024 + n0 + ng*2);
    acc2[0] += bov + xr.x;
    acc2[1] += bov + xr.y;
    __syncthreads();   // done reading alds

    alds[(ng*2 + 0)*128 + c] = acc2[0];
    alds[(ng*2 + 1)*128 + c] = acc2[1];
    __syncthreads();

    {   // LN stats: wave w owns row w
        const int lane = t & 63, w = t >> 6;
        const float v0 = alds[w*128 + lane];
        const float v1 = alds[w*128 + 64 + lane];
        const float s = wave_sum64(v0 + v1);
        const float q = wave_sum64(fmaf(v0, v0, v1*v1));
        if (lane == 0){
            const float mu  = s * 0.0078125f;
            const float var = q * 0.0078125f - mu*mu;
            stats[w]     = mu;
            stats[4 + w] = rsqrtf(var + 1e-5f);
        }
    }
    __syncthreads();

    const float g = gamma[c], b = beta[c];
    const int nn0 = ng*2;
    float2 o2;
    o2.x = (acc2[0] - stats[nn0])  * stats[4 + nn0]  * g + b;
    o2.y = (acc2[1] - stats[nn0+1])* stats[4 + nn0+1]* g + b;
    *(float2*)(out + (size_t)c*1024 + n0 + nn0) = o2;
}

extern "C" void kernel_launch(void* const* d_in, const int* in_sizes, int n_in,
                              void* d_out, int out_size, void* d_ws, size_t ws_size,
                              hipStream_t stream)
{
    const float* x     = (const float*)d_in[0];
    const float* xyz   = (const float*)d_in[1];
    const float* Wq    = (const float*)d_in[2];
    const float* Wk    = (const float*)d_in[3];
    const float* Wv    = (const float*)d_in[4];
    const float* Wp1   = (const float*)d_in[5];
    const float* bp1   = (const float*)d_in[6];
    const float* Wp2   = (const float*)d_in[7];
    const float* bp2   = (const float*)d_in[8];
    const float* Wo    = (const float*)d_in[9];
    const float* bo    = (const float*)d_in[10];
    const float* gamma = (const float*)d_in[11];
    const float* beta  = (const float*)d_in[12];
    float* ws  = (float*)d_ws;
    float* out = (float*)d_out;

    hipLaunchKernelGGL(k_prep,  dim3(64, 4),  dim3(256), 0, stream,
                       x, xyz, Wq, Wk, Wv, Wp1, bp1, Wp2, bp2, ws);
    hipLaunchKernelGGL(k_frag,  dim3(320),    dim3(256), 0, stream, xyz, ws);
    hipLaunchKernelGGL(k_attn,  dim3(64, 8),  dim3(256), 0, stream, ws, ws);
    hipLaunchKernelGGL(k_final, dim3(256),    dim3(256), 0, stream,
                       Wo, bo, x, gamma, beta, ws, out);
}